// Round 1
// baseline (845.395 us; speedup 1.0000x reference)
//
#include <hip/hip_runtime.h>
#include <cmath>

// Temporal Contrast Enhancement (Weger et al. 2019) — exact chunked-scan impl.
// x: [8,32,88200] fp32 -> 256 independent series of length T.
// Each envelope step is y = max/min(x, alpha*y + (1-alpha)*x), which composes
// as f(y) = max/min(A, B + G*y). We compute per-chunk transfers in parallel,
// scan them per-series, then replay chunks exactly from known init states.

static constexpr int   kT  = 88200;
static constexpr int   kS  = 256;                     // chunk length (mult of 4)
static constexpr int   kNC = (kT + kS - 1) / kS;      // 345 chunks/series
static constexpr float kSR = 44100.0f;

struct EnvP { float ad, bd, aa, ba, nuamp, reg; };

__device__ __forceinline__ EnvP make_params(const float* tauA, const float* tauD,
                                            const float* nu, const float* dbreg) {
  EnvP p;
  float td = fminf(fmaxf(tauD[0], 1.0f), 100.0f);
  td = fminf(fmaxf(td, 0.1f), 1000.0f) * 0.001f;      // seconds
  float ta = fminf(fmaxf(tauA[0], 1.0f), 100.0f);
  ta = fminf(fmaxf(ta, 0.1f), 1000.0f) * 0.001f;
  p.ad = expf(-1.0f / (td * kSR));
  p.aa = expf(-1.0f / (ta * kSR));
  p.bd = 1.0f - p.ad;
  p.ba = 1.0f - p.aa;
  p.nuamp = exp10f(fminf(fmaxf(nu[0],    -60.0f),   0.0f) * 0.05f);
  p.reg   = exp10f(fminf(fmaxf(dbreg[0], -120.0f), -60.0f) * 0.05f);
  return p;
}

// Pass 1: per chunk, compose decay-env transfer (A,B,G) from input |x|.
__global__ void k_comp_d(const float* __restrict__ x,
                         const float* tauA, const float* tauD,
                         const float* nu, const float* dbreg,
                         float* __restrict__ Ao, float* __restrict__ Bo,
                         float* __restrict__ Go, int nch) {
  int tid = blockIdx.x * blockDim.x + threadIdx.x;
  if (tid >= nch) return;
  EnvP p = make_params(tauA, tauD, nu, dbreg);
  int s = tid / kNC, c = tid - s * kNC;
  int t0 = c * kS;
  int n4 = min(kS, kT - t0) >> 2;
  const float4* xp = reinterpret_cast<const float4*>(x + (size_t)s * kT + t0);
  float A = -INFINITY, B = 0.0f, G = 1.0f;
#pragma unroll 2
  for (int i = 0; i < n4; ++i) {
    float4 v = xp[i];
    float vv[4] = {v.x, v.y, v.z, v.w};
#pragma unroll
    for (int j = 0; j < 4; ++j) {
      float xa = fabsf(vv[j]);
      float bx = p.bd * xa;
      A = fmaxf(xa, fmaf(p.ad, A, bx));   // decay-env run from -inf
      B = fmaf(p.ad, B, bx);              // linear part
      G *= p.ad;
    }
  }
  Ao[tid] = A; Bo[tid] = B; Go[tid] = G;
}

// Pass 2: replay decay env exactly (Yd known), compose attack-env transfer.
__global__ void k_comp_a(const float* __restrict__ x,
                         const float* tauA, const float* tauD,
                         const float* nu, const float* dbreg,
                         const float* __restrict__ Yd,
                         float* __restrict__ Ao, float* __restrict__ Bo,
                         float* __restrict__ Go, int nch) {
  int tid = blockIdx.x * blockDim.x + threadIdx.x;
  if (tid >= nch) return;
  EnvP p = make_params(tauA, tauD, nu, dbreg);
  int s = tid / kNC, c = tid - s * kNC;
  int t0 = c * kS;
  int n4 = min(kS, kT - t0) >> 2;
  const float4* xp = reinterpret_cast<const float4*>(x + (size_t)s * kT + t0);
  float yd = Yd[tid];
  float A = INFINITY, B = 0.0f, G = 1.0f;
#pragma unroll 2
  for (int i = 0; i < n4; ++i) {
    float4 v = xp[i];
    float vv[4] = {v.x, v.y, v.z, v.w};
#pragma unroll
    for (int j = 0; j < 4; ++j) {
      float xa = fabsf(vv[j]);
      yd = fmaxf(xa, fmaf(p.ad, yd, p.bd * xa));
      float by = p.ba * yd;
      A = fminf(yd, fmaf(p.aa, A, by));   // attack-env run from +inf
      B = fmaf(p.aa, B, by);
      G *= p.aa;
    }
  }
  Ao[tid] = A; Bo[tid] = B; Go[tid] = G;
}

// Pass 3: replay decay+attack envs, compose et-decay-env transfer.
__global__ void k_comp_e(const float* __restrict__ x,
                         const float* tauA, const float* tauD,
                         const float* nu, const float* dbreg,
                         const float* __restrict__ Yd, const float* __restrict__ Ya,
                         float* __restrict__ Ao, float* __restrict__ Bo,
                         float* __restrict__ Go, int nch) {
  int tid = blockIdx.x * blockDim.x + threadIdx.x;
  if (tid >= nch) return;
  EnvP p = make_params(tauA, tauD, nu, dbreg);
  int s = tid / kNC, c = tid - s * kNC;
  int t0 = c * kS;
  int n4 = min(kS, kT - t0) >> 2;
  const float4* xp = reinterpret_cast<const float4*>(x + (size_t)s * kT + t0);
  float yd = Yd[tid], ya = Ya[tid];
  float A = -INFINITY, B = 0.0f, G = 1.0f;
#pragma unroll 2
  for (int i = 0; i < n4; ++i) {
    float4 v = xp[i];
    float vv[4] = {v.x, v.y, v.z, v.w};
#pragma unroll
    for (int j = 0; j < 4; ++j) {
      float xa = fabsf(vv[j]);
      yd = fmaxf(xa, fmaf(p.ad, yd, p.bd * xa));
      ya = fminf(yd, fmaf(p.aa, ya, p.ba * yd));
      float et = fmaxf((yd - ya) - p.nuamp, 0.0f);
      float bx = p.bd * et;
      A = fmaxf(et, fmaf(p.ad, A, bx));
      B = fmaf(p.ad, B, bx);
      G *= p.ad;
    }
  }
  Ao[tid] = A; Bo[tid] = B; Go[tid] = G;
}

// Pass 4: replay everything, compute modulation, write output.
__global__ void k_final(const float* __restrict__ x,
                        const float* tauA, const float* tauD,
                        const float* nu, const float* dbreg,
                        const float* __restrict__ Yd, const float* __restrict__ Ya,
                        const float* __restrict__ Ye,
                        float* __restrict__ out, int nch) {
  int tid = blockIdx.x * blockDim.x + threadIdx.x;
  if (tid >= nch) return;
  EnvP p = make_params(tauA, tauD, nu, dbreg);
  int s = tid / kNC, c = tid - s * kNC;
  int t0 = c * kS;
  int n4 = min(kS, kT - t0) >> 2;
  const float4* xp = reinterpret_cast<const float4*>(x + (size_t)s * kT + t0);
  float4*       op = reinterpret_cast<float4*>(out + (size_t)s * kT + t0);
  float yd = Yd[tid], ya = Ya[tid], ye = Ye[tid];
#pragma unroll 2
  for (int i = 0; i < n4; ++i) {
    float4 v = xp[i];
    float vv[4] = {v.x, v.y, v.z, v.w};
    float oo[4];
#pragma unroll
    for (int j = 0; j < 4; ++j) {
      float xa = fabsf(vv[j]);
      yd = fmaxf(xa, fmaf(p.ad, yd, p.bd * xa));
      ya = fminf(yd, fmaf(p.aa, ya, p.ba * yd));
      float et = fmaxf((yd - ya) - p.nuamp, 0.0f);
      ye = fmaxf(et, fmaf(p.ad, ye, p.bd * et));
      float mod = et / (ye + p.reg);
      oo[j] = vv[j] * mod;
    }
    op[i] = make_float4(oo[0], oo[1], oo[2], oo[3]);
  }
}

// Per-series sequential scan over chunk transfers. 16-wide batched loads to
// amortize memory latency (only 4 waves run this kernel).
__global__ void k_scan(const float* __restrict__ A, const float* __restrict__ B,
                       const float* __restrict__ G, float* __restrict__ Y,
                       int attack, int nseries) {
  int s = blockIdx.x * blockDim.x + threadIdx.x;
  if (s >= nseries) return;
  long base = (long)s * kNC;
  float y = 0.0f;
  constexpr int BATCH = 16;
  for (int c = 0; c < kNC; c += BATCH) {
    float a[BATCH], b[BATCH], g[BATCH];
    int n = min(BATCH, kNC - c);
#pragma unroll
    for (int k = 0; k < BATCH; ++k)
      if (k < n) { a[k] = A[base + c + k]; b[k] = B[base + c + k]; g[k] = G[base + c + k]; }
#pragma unroll
    for (int k = 0; k < BATCH; ++k)
      if (k < n) {
        Y[base + c + k] = y;                 // init state for chunk c+k
        float t = fmaf(g[k], y, b[k]);
        y = attack ? fminf(a[k], t) : fmaxf(a[k], t);
      }
  }
}

extern "C" void kernel_launch(void* const* d_in, const int* in_sizes, int n_in,
                              void* d_out, int out_size, void* d_ws, size_t ws_size,
                              hipStream_t stream) {
  const float* x     = (const float*)d_in[0];
  const float* tauA  = (const float*)d_in[1];
  const float* tauD  = (const float*)d_in[2];
  const float* nu    = (const float*)d_in[3];
  const float* dbreg = (const float*)d_in[4];
  float* out = (float*)d_out;

  int nseries = in_sizes[0] / kT;         // 256
  int nch     = nseries * kNC;            // 88320

  float* wsf = (float*)d_ws;              // 6 * nch floats ≈ 2.1 MB
  float* A  = wsf;
  float* B  = wsf + (size_t)nch;
  float* G  = wsf + (size_t)2 * nch;
  float* Yd = wsf + (size_t)3 * nch;
  float* Ya = wsf + (size_t)4 * nch;
  float* Ye = wsf + (size_t)5 * nch;

  int grid = (nch + 255) / 256;

  k_comp_d<<<grid, 256, 0, stream>>>(x, tauA, tauD, nu, dbreg, A, B, G, nch);
  k_scan  <<<1, 256, 0, stream>>>(A, B, G, Yd, 0, nseries);
  k_comp_a<<<grid, 256, 0, stream>>>(x, tauA, tauD, nu, dbreg, Yd, A, B, G, nch);
  k_scan  <<<1, 256, 0, stream>>>(A, B, G, Ya, 1, nseries);
  k_comp_e<<<grid, 256, 0, stream>>>(x, tauA, tauD, nu, dbreg, Yd, Ya, A, B, G, nch);
  k_scan  <<<1, 256, 0, stream>>>(A, B, G, Ye, 0, nseries);
  k_final <<<grid, 256, 0, stream>>>(x, tauA, tauD, nu, dbreg, Yd, Ya, Ye, out, nch);
}

// Round 2
// 320.845 us; speedup vs baseline: 2.6349x; 2.6349x over previous
//
#include <hip/hip_runtime.h>
#include <cmath>

// Temporal Contrast Enhancement — chunked associative-scan implementation.
// x: [8,32,88200] fp32 -> 256 independent series of length T=88200.
// Envelope step y = op(x, alpha*y + (1-alpha)*x) composes as f(y)=op(A, B+G*y);
// G per full chunk is alpha^S (analytic, not stored).
// Pipeline: comp_d -> scan_d -> comp_a -> scan_a -> comp_e -> scan_e -> final.
// Scans are block-parallel (one workgroup per series, Hillis-Steele in LDS) —
// R1's sequential scan spilled its batching arrays to scratch (VGPR=36) and
// cost 193us per scan; this version keeps everything in registers/LDS.

static constexpr int   kT      = 88200;
static constexpr float kSR     = 44100.0f;
static constexpr int   kMaxCPT = 6;          // ceil(ceil(88200/64)/256)

struct EnvP { float ad, bd, aa, ba, nuamp, reg; };

__device__ __forceinline__ EnvP make_params(const float* tauA, const float* tauD,
                                            const float* nu, const float* dbreg) {
  EnvP p;
  float td = fminf(fmaxf(tauD[0], 1.0f), 100.0f);
  td = fminf(fmaxf(td, 0.1f), 1000.0f) * 0.001f;
  float ta = fminf(fmaxf(tauA[0], 1.0f), 100.0f);
  ta = fminf(fmaxf(ta, 0.1f), 1000.0f) * 0.001f;
  p.ad = expf(-1.0f / (td * kSR));
  p.aa = expf(-1.0f / (ta * kSR));
  p.bd = 1.0f - p.ad;
  p.ba = 1.0f - p.aa;
  p.nuamp = exp10f(fminf(fmaxf(nu[0],    -60.0f),   0.0f) * 0.05f);
  p.reg   = exp10f(fminf(fmaxf(dbreg[0], -120.0f), -60.0f) * 0.05f);
  return p;
}

// ---- Pass 1: per-chunk decay-env transfer (A,B) from |x| -------------------
__global__ void k_comp_d(const float* __restrict__ x,
                         const float* tauA, const float* tauD,
                         const float* nu, const float* dbreg,
                         float* __restrict__ Ao, float* __restrict__ Bo,
                         int S, int nc, int nch) {
  int tid = blockIdx.x * blockDim.x + threadIdx.x;
  if (tid >= nch) return;
  EnvP p = make_params(tauA, tauD, nu, dbreg);
  int s = tid / nc, c = tid - s * nc;
  int t0 = c * S;
  int n4 = min(S, kT - t0) >> 2;
  const float4* xp = reinterpret_cast<const float4*>(x + (size_t)s * kT + t0);
  float A = -INFINITY, B = 0.0f;
#pragma unroll 2
  for (int i = 0; i < n4; ++i) {
    float4 v = xp[i];
    float vv[4] = {v.x, v.y, v.z, v.w};
#pragma unroll
    for (int j = 0; j < 4; ++j) {
      float xa = fabsf(vv[j]);
      float bx = p.bd * xa;
      A = fmaxf(xa, fmaf(p.ad, A, bx));
      B = fmaf(p.ad, B, bx);
    }
  }
  Ao[tid] = A; Bo[tid] = B;
}

// ---- Pass 2: replay decay env, compose attack-env transfer -----------------
__global__ void k_comp_a(const float* __restrict__ x,
                         const float* tauA, const float* tauD,
                         const float* nu, const float* dbreg,
                         const float* __restrict__ Yd,
                         float* __restrict__ Ao, float* __restrict__ Bo,
                         int S, int nc, int nch) {
  int tid = blockIdx.x * blockDim.x + threadIdx.x;
  if (tid >= nch) return;
  EnvP p = make_params(tauA, tauD, nu, dbreg);
  int s = tid / nc, c = tid - s * nc;
  int t0 = c * S;
  int n4 = min(S, kT - t0) >> 2;
  const float4* xp = reinterpret_cast<const float4*>(x + (size_t)s * kT + t0);
  float yd = Yd[tid];
  float A = INFINITY, B = 0.0f;
#pragma unroll 2
  for (int i = 0; i < n4; ++i) {
    float4 v = xp[i];
    float vv[4] = {v.x, v.y, v.z, v.w};
#pragma unroll
    for (int j = 0; j < 4; ++j) {
      float xa = fabsf(vv[j]);
      yd = fmaxf(xa, fmaf(p.ad, yd, p.bd * xa));
      float by = p.ba * yd;
      A = fminf(yd, fmaf(p.aa, A, by));
      B = fmaf(p.aa, B, by);
    }
  }
  Ao[tid] = A; Bo[tid] = B;
}

// ---- Pass 3: replay decay+attack, compose et-decay transfer ----------------
__global__ void k_comp_e(const float* __restrict__ x,
                         const float* tauA, const float* tauD,
                         const float* nu, const float* dbreg,
                         const float* __restrict__ Yd, const float* __restrict__ Ya,
                         float* __restrict__ Ao, float* __restrict__ Bo,
                         int S, int nc, int nch) {
  int tid = blockIdx.x * blockDim.x + threadIdx.x;
  if (tid >= nch) return;
  EnvP p = make_params(tauA, tauD, nu, dbreg);
  int s = tid / nc, c = tid - s * nc;
  int t0 = c * S;
  int n4 = min(S, kT - t0) >> 2;
  const float4* xp = reinterpret_cast<const float4*>(x + (size_t)s * kT + t0);
  float yd = Yd[tid], ya = Ya[tid];
  float A = -INFINITY, B = 0.0f;
#pragma unroll 2
  for (int i = 0; i < n4; ++i) {
    float4 v = xp[i];
    float vv[4] = {v.x, v.y, v.z, v.w};
#pragma unroll
    for (int j = 0; j < 4; ++j) {
      float xa = fabsf(vv[j]);
      yd = fmaxf(xa, fmaf(p.ad, yd, p.bd * xa));
      ya = fminf(yd, fmaf(p.aa, ya, p.ba * yd));
      float et = fmaxf((yd - ya) - p.nuamp, 0.0f);
      float bx = p.bd * et;
      A = fmaxf(et, fmaf(p.ad, A, bx));
      B = fmaf(p.ad, B, bx);
    }
  }
  Ao[tid] = A; Bo[tid] = B;
}

// ---- Pass 4: replay everything, write output -------------------------------
__global__ void k_final(const float* __restrict__ x,
                        const float* tauA, const float* tauD,
                        const float* nu, const float* dbreg,
                        const float* __restrict__ Yd, const float* __restrict__ Ya,
                        const float* __restrict__ Ye,
                        float* __restrict__ out, int S, int nc, int nch) {
  int tid = blockIdx.x * blockDim.x + threadIdx.x;
  if (tid >= nch) return;
  EnvP p = make_params(tauA, tauD, nu, dbreg);
  int s = tid / nc, c = tid - s * nc;
  int t0 = c * S;
  int n4 = min(S, kT - t0) >> 2;
  const float4* xp = reinterpret_cast<const float4*>(x + (size_t)s * kT + t0);
  float4*       op = reinterpret_cast<float4*>(out + (size_t)s * kT + t0);
  float yd = Yd[tid], ya = Ya[tid], ye = Ye[tid];
#pragma unroll 2
  for (int i = 0; i < n4; ++i) {
    float4 v = xp[i];
    float vv[4] = {v.x, v.y, v.z, v.w};
    float oo[4];
#pragma unroll
    for (int j = 0; j < 4; ++j) {
      float xa = fabsf(vv[j]);
      yd = fmaxf(xa, fmaf(p.ad, yd, p.bd * xa));
      ya = fminf(yd, fmaf(p.aa, ya, p.ba * yd));
      float et = fmaxf((yd - ya) - p.nuamp, 0.0f);
      ye = fmaxf(et, fmaf(p.ad, ye, p.bd * et));
      oo[j] = vv[j] * (et / (ye + p.reg));
    }
    op[i] = make_float4(oo[0], oo[1], oo[2], oo[3]);
  }
}

// ---- Block-parallel scan: one workgroup per series -------------------------
// Thread t owns chunks [t*CPT, (t+1)*CPT); serial compose in regs, block-level
// Hillis-Steele scan of (A,B,G) triples in LDS, then replay to emit Y (the
// env state at each chunk's start). ATTACK=1 -> min-compose with alpha_a.
template <int ATTACK>
__global__ void k_scan_par(const float* __restrict__ A, const float* __restrict__ B,
                           float* __restrict__ Y,
                           const float* tauA, const float* tauD,
                           const float* nu, const float* dbreg,
                           int S, int nc) {
  EnvP p = make_params(tauA, tauD, nu, dbreg);
  const float alpha = ATTACK ? p.aa : p.ad;
  const float ID_A  = ATTACK ? INFINITY : -INFINITY;
  int s = blockIdx.x, t = threadIdx.x;
  long base = (long)s * nc;
  int CPT = (nc + 255) >> 8;                 // <= kMaxCPT for S>=64
  int lastlen = kT - (nc - 1) * S;
  float gS = powf(alpha, (float)S);
  float gL = powf(alpha, (float)lastlen);

  float ca[kMaxCPT], cb[kMaxCPT], cg[kMaxCPT];
  float a = ID_A, b = 0.0f, g = 1.0f;
#pragma unroll
  for (int k = 0; k < kMaxCPT; ++k) {
    if (k >= CPT) break;
    int c = t * CPT + k;
    if (c < nc) { ca[k] = A[base + c]; cb[k] = B[base + c]; cg[k] = (c == nc - 1) ? gL : gS; }
    else        { ca[k] = ID_A;        cb[k] = 0.0f;        cg[k] = 1.0f; }
    // acc = f_k ∘ acc
    float na = ATTACK ? fminf(ca[k], fmaf(cg[k], a, cb[k]))
                      : fmaxf(ca[k], fmaf(cg[k], a, cb[k]));
    b = fmaf(cg[k], b, cb[k]);
    g = cg[k] * g;
    a = na;
  }

  __shared__ float sA[256], sB[256], sG[256];
  sA[t] = a; sB[t] = b; sG[t] = g;
  __syncthreads();
#pragma unroll
  for (int d = 1; d < 256; d <<= 1) {
    float pa = 0.0f, pb = 0.0f, pg = 0.0f;
    if (t >= d) { pa = sA[t - d]; pb = sB[t - d]; pg = sG[t - d]; }
    __syncthreads();
    if (t >= d) {
      float na = ATTACK ? fminf(a, fmaf(g, pa, b)) : fmaxf(a, fmaf(g, pa, b));
      b = fmaf(g, pb, b);
      g = g * pg;
      a = na;
      sA[t] = a; sB[t] = b; sG[t] = g;
    }
    __syncthreads();
  }

  float ea, eb, eg;                           // exclusive prefix transfer
  if (t == 0) { ea = ID_A; eb = 0.0f; eg = 1.0f; }
  else        { ea = sA[t - 1]; eb = sB[t - 1]; eg = sG[t - 1]; }

#pragma unroll
  for (int k = 0; k < kMaxCPT; ++k) {
    if (k >= CPT) break;
    int c = t * CPT + k;
    if (c >= nc) break;
    Y[base + c] = ATTACK ? fminf(ea, eb) : fmaxf(ea, eb);   // eval at y0=0
    float na = ATTACK ? fminf(ca[k], fmaf(cg[k], ea, cb[k]))
                      : fmaxf(ca[k], fmaf(cg[k], ea, cb[k]));
    eb = fmaf(cg[k], eb, cb[k]);
    eg = cg[k] * eg;
    ea = na;
  }
}

extern "C" void kernel_launch(void* const* d_in, const int* in_sizes, int n_in,
                              void* d_out, int out_size, void* d_ws, size_t ws_size,
                              hipStream_t stream) {
  const float* x     = (const float*)d_in[0];
  const float* tauA  = (const float*)d_in[1];
  const float* tauD  = (const float*)d_in[2];
  const float* nu    = (const float*)d_in[3];
  const float* dbreg = (const float*)d_in[4];
  float* out = (float*)d_out;

  int nseries = in_sizes[0] / kT;            // 256

  // Pick chunk size S (mult of 4): prefer 64 for occupancy; fall back if ws
  // can't hold 5 arrays of nseries*ceil(T/S) floats.
  int S = 64;
  for (int cand : {64, 128, 256}) {
    S = cand;
    long nc_c = (kT + cand - 1) / cand;
    if ((size_t)5 * nseries * nc_c * sizeof(float) <= ws_size) break;
  }
  int nc  = (kT + S - 1) / S;
  int nch = nseries * nc;

  float* wsf = (float*)d_ws;
  float* A  = wsf;
  float* B  = wsf + (size_t)nch;
  float* Yd = wsf + (size_t)2 * nch;
  float* Ya = wsf + (size_t)3 * nch;
  float* Ye = wsf + (size_t)4 * nch;

  int grid = (nch + 255) / 256;

  k_comp_d<<<grid, 256, 0, stream>>>(x, tauA, tauD, nu, dbreg, A, B, S, nc, nch);
  k_scan_par<0><<<nseries, 256, 0, stream>>>(A, B, Yd, tauA, tauD, nu, dbreg, S, nc);
  k_comp_a<<<grid, 256, 0, stream>>>(x, tauA, tauD, nu, dbreg, Yd, A, B, S, nc, nch);
  k_scan_par<1><<<nseries, 256, 0, stream>>>(A, B, Ya, tauA, tauD, nu, dbreg, S, nc);
  k_comp_e<<<grid, 256, 0, stream>>>(x, tauA, tauD, nu, dbreg, Yd, Ya, A, B, S, nc, nch);
  k_scan_par<0><<<nseries, 256, 0, stream>>>(A, B, Ye, tauA, tauD, nu, dbreg, S, nc);
  k_final <<<grid, 256, 0, stream>>>(x, tauA, tauD, nu, dbreg, Yd, Ya, Ye, out, S, nc, nch);
}

// Round 3
// 234.951 us; speedup vs baseline: 3.5982x; 1.3656x over previous
//
#include <hip/hip_runtime.h>
#include <cmath>

// Temporal Contrast Enhancement — chunked associative-scan, LDS-staged tiles.
// x: [8,32,88200] fp32 = 256 series of T=88200. Chunk size S divides T exactly
// (S=40 -> nc=2205), so chunks are contiguous in global memory across series.
// Each block of 256 threads owns one contiguous tile of 256 chunks:
//   coalesced float4 global->LDS stage, per-thread recurrence out of LDS
//   (padded stride S+4 -> conflict-free float4 LDS reads), coalesced store.
// R2's thread-per-chunk global reads (16B per lane at 256B lane stride) gave
// 1.56x HBM over-fetch and 22% of peak; this removes the scatter entirely.

static constexpr int   kT  = 88200;
static constexpr float kSR = 44100.0f;

struct EnvP { float ad, bd, aa, ba, nuamp, reg; };

__device__ __forceinline__ EnvP make_params(const float* tauA, const float* tauD,
                                            const float* nu, const float* dbreg) {
  EnvP p;
  float td = fminf(fmaxf(tauD[0], 1.0f), 100.0f);
  td = fminf(fmaxf(td, 0.1f), 1000.0f) * 0.001f;
  float ta = fminf(fmaxf(tauA[0], 1.0f), 100.0f);
  ta = fminf(fmaxf(ta, 0.1f), 1000.0f) * 0.001f;
  p.ad = expf(-1.0f / (td * kSR));
  p.aa = expf(-1.0f / (ta * kSR));
  p.bd = 1.0f - p.ad;
  p.ba = 1.0f - p.aa;
  p.nuamp = exp10f(fminf(fmaxf(nu[0],    -60.0f),   0.0f) * 0.05f);
  p.reg   = exp10f(fminf(fmaxf(dbreg[0], -120.0f), -60.0f) * 0.05f);
  return p;
}

// MODE: 0=comp_d (A,B of decay env from |x|)
//       1=comp_a (replay yd; A,B of attack env)
//       2=comp_e (replay yd,ya; A,B of decay env on et)
//       3=final  (replay all; out = x * et/(ye+reg))
template <int S, int MODE>
__global__ __launch_bounds__(256)
void k_pass(const float* __restrict__ x,
            const float* tauA, const float* tauD,
            const float* nu, const float* dbreg,
            const float* __restrict__ Yd, const float* __restrict__ Ya,
            const float* __restrict__ Ye,
            float* __restrict__ O0, float* __restrict__ O1) {
  constexpr int PADS = S + 4;                 // padded chunk stride (floats)
  __shared__ float lds[256 * PADS];
  const int t   = threadIdx.x;
  const int blk = blockIdx.x;
  const size_t tileBase = (size_t)blk * (256 * S);
  const float4* xg = reinterpret_cast<const float4*>(x + tileBase);

  // ---- stage tile: coalesced global -> padded LDS ----
#pragma unroll
  for (int i = 0; i < S / 4; ++i) {
    int idx = t + i * 256;                    // float4 index within tile
    float4 v = xg[idx];
    int chunk = (idx * 4) / S;
    int off   = idx * 4 - chunk * S;
    *reinterpret_cast<float4*>(&lds[chunk * PADS + off]) = v;
  }
  __syncthreads();

  EnvP p = make_params(tauA, tauD, nu, dbreg);
  const int gchunk = blk * 256 + t;
  float* my = &lds[t * PADS];

  if (MODE == 0) {
    float A = -INFINITY, B = 0.0f;
#pragma unroll 2
    for (int i = 0; i < S / 4; ++i) {
      float4 v = *reinterpret_cast<const float4*>(&my[4 * i]);
      float vv[4] = {v.x, v.y, v.z, v.w};
#pragma unroll
      for (int j = 0; j < 4; ++j) {
        float xa = fabsf(vv[j]);
        float bx = p.bd * xa;
        A = fmaxf(xa, fmaf(p.ad, A, bx));
        B = fmaf(p.ad, B, bx);
      }
    }
    O0[gchunk] = A; O1[gchunk] = B;
  } else if (MODE == 1) {
    float yd = Yd[gchunk];
    float A = INFINITY, B = 0.0f;
#pragma unroll 2
    for (int i = 0; i < S / 4; ++i) {
      float4 v = *reinterpret_cast<const float4*>(&my[4 * i]);
      float vv[4] = {v.x, v.y, v.z, v.w};
#pragma unroll
      for (int j = 0; j < 4; ++j) {
        float xa = fabsf(vv[j]);
        yd = fmaxf(xa, fmaf(p.ad, yd, p.bd * xa));
        float by = p.ba * yd;
        A = fminf(yd, fmaf(p.aa, A, by));
        B = fmaf(p.aa, B, by);
      }
    }
    O0[gchunk] = A; O1[gchunk] = B;
  } else if (MODE == 2) {
    float yd = Yd[gchunk], ya = Ya[gchunk];
    float A = -INFINITY, B = 0.0f;
#pragma unroll 2
    for (int i = 0; i < S / 4; ++i) {
      float4 v = *reinterpret_cast<const float4*>(&my[4 * i]);
      float vv[4] = {v.x, v.y, v.z, v.w};
#pragma unroll
      for (int j = 0; j < 4; ++j) {
        float xa = fabsf(vv[j]);
        yd = fmaxf(xa, fmaf(p.ad, yd, p.bd * xa));
        ya = fminf(yd, fmaf(p.aa, ya, p.ba * yd));
        float et = fmaxf((yd - ya) - p.nuamp, 0.0f);
        float bx = p.bd * et;
        A = fmaxf(et, fmaf(p.ad, A, bx));
        B = fmaf(p.ad, B, bx);
      }
    }
    O0[gchunk] = A; O1[gchunk] = B;
  } else {
    float yd = Yd[gchunk], ya = Ya[gchunk], ye = Ye[gchunk];
#pragma unroll 2
    for (int i = 0; i < S / 4; ++i) {
      float4 v = *reinterpret_cast<const float4*>(&my[4 * i]);
      float vv[4] = {v.x, v.y, v.z, v.w};
      float oo[4];
#pragma unroll
      for (int j = 0; j < 4; ++j) {
        float xa = fabsf(vv[j]);
        yd = fmaxf(xa, fmaf(p.ad, yd, p.bd * xa));
        ya = fminf(yd, fmaf(p.aa, ya, p.ba * yd));
        float et = fmaxf((yd - ya) - p.nuamp, 0.0f);
        ye = fmaxf(et, fmaf(p.ad, ye, p.bd * et));
        oo[j] = vv[j] * (et / (ye + p.reg));
      }
      *reinterpret_cast<float4*>(&my[4 * i]) = make_float4(oo[0], oo[1], oo[2], oo[3]);
    }
    __syncthreads();
    float4* og = reinterpret_cast<float4*>(O0 + tileBase);
#pragma unroll
    for (int i = 0; i < S / 4; ++i) {
      int idx = t + i * 256;
      int chunk = (idx * 4) / S;
      int off   = idx * 4 - chunk * S;
      og[idx] = *reinterpret_cast<const float4*>(&lds[chunk * PADS + off]);
    }
  }
}

// ---- Block-parallel scan: one workgroup per series -------------------------
template <int S, int ATTACK>
__global__ __launch_bounds__(256)
void k_scan(const float* __restrict__ A, const float* __restrict__ B,
            float* __restrict__ Y,
            const float* tauA, const float* tauD,
            const float* nu, const float* dbreg) {
  constexpr int NC  = kT / S;
  constexpr int CPT = (NC + 255) / 256;
  EnvP p = make_params(tauA, tauD, nu, dbreg);
  const float alpha = ATTACK ? p.aa : p.ad;
  const float ID_A  = ATTACK ? INFINITY : -INFINITY;
  int s = blockIdx.x, t = threadIdx.x;
  long base = (long)s * NC;
  float gS = powf(alpha, (float)S);

  float ca[CPT], cb[CPT];
  float a = ID_A, b = 0.0f, g = 1.0f;
#pragma unroll
  for (int k = 0; k < CPT; ++k) {
    int c = t * CPT + k;
    if (c < NC) { ca[k] = A[base + c]; cb[k] = B[base + c]; }
    else        { ca[k] = ID_A;        cb[k] = 0.0f; }
    float cg = (c < NC) ? gS : 1.0f;
    float na = ATTACK ? fminf(ca[k], fmaf(cg, a, cb[k]))
                      : fmaxf(ca[k], fmaf(cg, a, cb[k]));
    b = fmaf(cg, b, cb[k]);
    g = cg * g;
    a = na;
  }

  __shared__ float sA[256], sB[256], sG[256];
  sA[t] = a; sB[t] = b; sG[t] = g;
  __syncthreads();
#pragma unroll
  for (int d = 1; d < 256; d <<= 1) {
    float pa = 0.0f, pb = 0.0f, pg = 0.0f;
    if (t >= d) { pa = sA[t - d]; pb = sB[t - d]; pg = sG[t - d]; }
    __syncthreads();
    if (t >= d) {
      float na = ATTACK ? fminf(a, fmaf(g, pa, b)) : fmaxf(a, fmaf(g, pa, b));
      b = fmaf(g, pb, b);
      g = g * pg;
      a = na;
      sA[t] = a; sB[t] = b; sG[t] = g;
    }
    __syncthreads();
  }

  float ea, eb;
  if (t == 0) { ea = ID_A; eb = 0.0f; }
  else        { ea = sA[t - 1]; eb = sB[t - 1]; }

#pragma unroll
  for (int k = 0; k < CPT; ++k) {
    int c = t * CPT + k;
    if (c >= NC) break;
    Y[base + c] = ATTACK ? fminf(ea, eb) : fmaxf(ea, eb);   // eval at y0=0
    float na = ATTACK ? fminf(ca[k], fmaf(gS, ea, cb[k]))
                      : fmaxf(ca[k], fmaf(gS, ea, cb[k]));
    eb = fmaf(gS, eb, cb[k]);
    ea = na;
  }
}

template <int S>
static void run_pipeline(const float* x, const float* tauA, const float* tauD,
                         const float* nu, const float* dbreg, float* out,
                         float* wsf, int nseries, hipStream_t stream) {
  const int nc  = kT / S;
  const int nch = nseries * nc;
  float* A  = wsf;
  float* B  = wsf + (size_t)nch;
  float* Yd = wsf + (size_t)2 * nch;
  float* Ya = wsf + (size_t)3 * nch;
  float* Ye = wsf + (size_t)4 * nch;
  const int grid = nch / 256;               // nseries=256 -> exact

  k_pass<S, 0><<<grid, 256, 0, stream>>>(x, tauA, tauD, nu, dbreg, nullptr, nullptr, nullptr, A, B);
  k_scan<S, 0><<<nseries, 256, 0, stream>>>(A, B, Yd, tauA, tauD, nu, dbreg);
  k_pass<S, 1><<<grid, 256, 0, stream>>>(x, tauA, tauD, nu, dbreg, Yd, nullptr, nullptr, A, B);
  k_scan<S, 1><<<nseries, 256, 0, stream>>>(A, B, Ya, tauA, tauD, nu, dbreg);
  k_pass<S, 2><<<grid, 256, 0, stream>>>(x, tauA, tauD, nu, dbreg, Yd, Ya, nullptr, A, B);
  k_scan<S, 0><<<nseries, 256, 0, stream>>>(A, B, Ye, tauA, tauD, nu, dbreg);
  k_pass<S, 3><<<grid, 256, 0, stream>>>(x, tauA, tauD, nu, dbreg, Yd, Ya, Ye, out, nullptr);
}

extern "C" void kernel_launch(void* const* d_in, const int* in_sizes, int n_in,
                              void* d_out, int out_size, void* d_ws, size_t ws_size,
                              hipStream_t stream) {
  const float* x     = (const float*)d_in[0];
  const float* tauA  = (const float*)d_in[1];
  const float* tauD  = (const float*)d_in[2];
  const float* nu    = (const float*)d_in[3];
  const float* dbreg = (const float*)d_in[4];
  float* out = (float*)d_out;
  float* wsf = (float*)d_ws;
  int nseries = in_sizes[0] / kT;           // 256

  auto fits = [&](int S) {
    return (size_t)5 * nseries * (kT / S) * sizeof(float) <= ws_size;
  };
  // S must divide kT=88200 and be a multiple of 4. Prefer small S (more
  // parallelism, 3 blocks/CU at 45KB LDS).
  if      (fits(40))  run_pipeline<40>(x, tauA, tauD, nu, dbreg, out, wsf, nseries, stream);
  else if (fits(56))  run_pipeline<56 >(x, tauA, tauD, nu, dbreg, out, wsf, nseries, stream);
  else if (fits(72))  run_pipeline<72 >(x, tauA, tauD, nu, dbreg, out, wsf, nseries, stream);
  else                run_pipeline<120>(x, tauA, tauD, nu, dbreg, out, wsf, nseries, stream);
}